// Round 15
// baseline (140.239 us; speedup 1.0000x reference)
//
#include <hip/hip_runtime.h>
#include <hip/hip_bf16.h>
#include <stdint.h>

typedef unsigned short u16;
typedef short short8 __attribute__((ext_vector_type(8)));
typedef float f32x4 __attribute__((ext_vector_type(4)));
typedef float f32x16 __attribute__((ext_vector_type(16)));
typedef u16 u16x4 __attribute__((ext_vector_type(4)));
typedef unsigned uint32x4 __attribute__((ext_vector_type(4)));

#define SCLOG 0.18033688011112042f  // 0.125 * log2(e)
#define MFMA32(A, B, C) __builtin_amdgcn_mfma_f32_32x32x16_bf16(A, B, C, 0, 0, 0)

static __device__ __forceinline__ u16 f2bf(float f) {
  unsigned u = __float_as_uint(f);
  unsigned rnd = 0x7fffu + ((u >> 16) & 1u);
  return (u16)((u + rnd) >> 16);
}

// packed f32x2 -> bf16x2 via HW v_cvt_pk_bf16_f32 (no builtin on gfx950; T12/m240)
static __device__ __forceinline__ unsigned pk_bf16(float a, float b) {
  unsigned r;
  asm("v_cvt_pk_bf16_f32 %0, %1, %2" : "=v"(r) : "v"(a), "v"(b));
  return r;
}

static __device__ __forceinline__ void gload_lds16(const void* g, void* l) {
  __builtin_amdgcn_global_load_lds(
      (const __attribute__((address_space(1))) unsigned int*)g,
      (__attribute__((address_space(3))) unsigned int*)l, 16, 0, 0);
}

// ---------------------------------------------------------------- fused prep
__global__ __launch_bounds__(256) void prep_kernel(
    const float* __restrict__ hs, const int* __restrict__ mask,
    const float* __restrict__ Wq, const float* __restrict__ Wk,
    const float* __restrict__ Wv, const float* __restrict__ Wo,
    u16* __restrict__ X, u16* __restrict__ WT,
    unsigned long long* __restrict__ bits) {
  __shared__ float tile[32][33];
  const int bid = blockIdx.x;
  const int tid = threadIdx.x;
  if (bid < 4096) {
    const int i = bid * 256 + tid;
    const float4 v = reinterpret_cast<const float4*>(hs)[i];
    u16x4 o;
    o[0] = f2bf(v.x); o[1] = f2bf(v.y); o[2] = f2bf(v.z); o[3] = f2bf(v.w);
    reinterpret_cast<u16x4*>(X)[i] = o;
  } else if (bid < 8192) {
    const int B = bid - 4096;
    const int z = B >> 10, y = (B >> 5) & 31, x = B & 31;
    const float* src = (z == 0) ? Wq : (z == 1) ? Wk : (z == 2) ? Wv : Wo;
    u16* dst = WT + (size_t)z * 1024 * 1024;
    const int row0 = y * 32, col0 = x * 32;
    const int tx = tid & 31, ty = tid >> 5;
#pragma unroll
    for (int i = 0; i < 4; ++i)
      tile[ty + i * 8][tx] = src[(size_t)(row0 + ty + i * 8) * 1024 + col0 + tx];
    __syncthreads();
#pragma unroll
    for (int i = 0; i < 4; ++i) {
      const int r = ty + i * 8;
      dst[(size_t)(col0 + r) * 1024 + row0 + tx] = f2bf(tile[tx][r]);
    }
  } else {
    const int gw = (bid - 8192) * 4 + (tid >> 6);
    const int lane = tid & 63;
    const int q = gw >> 5, w = gw & 31;
    const int mv = mask[(size_t)q * 2048 + w * 64 + lane];
    const unsigned long long bal = __ballot(mv != 0);
    if (lane == 0) bits[(size_t)q * 32 + w] = bal;
  }
}

// ---------------------------------------------------------------- GEMM QKV
// (R12: BK=32 2-phase + XCD swizzle, swapped-operand MFMA, uint2 epilogue.)
__global__ __launch_bounds__(256) void gemm_qkv_kernel(
    const u16* __restrict__ X, const u16* __restrict__ WT,
    const float* __restrict__ bq, const float* __restrict__ bk, const float* __restrict__ bv,
    u16* __restrict__ Qb, u16* __restrict__ Kb, u16* __restrict__ Vb) {
  __shared__ u16 As[128 * 32];
  __shared__ u16 Bs[128 * 32];
  const int tid = threadIdx.x;
  const int lane = tid & 63, wid = tid >> 6;
  const int l15 = lane & 15, lg = lane >> 4;
  const int wg = blockIdx.x;            // 768 = 8 XCDs x (3 n-panels x 32 m)
  const int xcd = wg & 7, idx = wg >> 3;
  const int n0 = (xcd * 3 + (idx >> 5)) * 128;
  const int m0 = (idx & 31) * 128;
  const int wr = wid >> 1, wc = wid & 1;

  f32x4 acc[4][4] = {};

  for (int kt = 0; kt < 32; ++kt) {
    __syncthreads();
#pragma unroll
    for (int p = 0; p < 2; ++p) {
      const int c = p * 256 + tid;
      const int r = c >> 2, ch = c & 3;
      gload_lds16(X + (size_t)(m0 + r) * 1024 + kt * 32 + ch * 8,
                  &As[(p * 256 + wid * 64) * 8]);
      gload_lds16(WT + (size_t)(n0 + r) * 1024 + kt * 32 + ch * 8,
                  &Bs[(p * 256 + wid * 64) * 8]);
    }
    __syncthreads();
    short8 af[4], bfr[4];
#pragma unroll
    for (int i = 0; i < 4; ++i) {
      af[i] = *reinterpret_cast<const short8*>(&As[(wr * 64 + i * 16 + l15) * 32 + lg * 8]);
      bfr[i] = *reinterpret_cast<const short8*>(&Bs[(wc * 64 + i * 16 + l15) * 32 + lg * 8]);
    }
#pragma unroll
    for (int i = 0; i < 4; ++i)
#pragma unroll
      for (int j = 0; j < 4; ++j)
        acc[i][j] = __builtin_amdgcn_mfma_f32_16x16x32_bf16(bfr[j], af[i], acc[i][j], 0, 0, 0);
  }

#pragma unroll
  for (int i = 0; i < 4; ++i) {
    const int m = m0 + wr * 64 + i * 16 + l15;
    const int bb = m >> 11, t = m & 2047;
#pragma unroll
    for (int j = 0; j < 4; ++j) {
      const int n = n0 + wc * 64 + j * 16 + lg * 4;
      const float* bsrc = (n < 1024) ? (bq + n) : (n < 2048) ? (bk + n - 1024) : (bv + n - 2048);
      const float4 b4 = *reinterpret_cast<const float4*>(bsrc);
      const float scl = (n < 1024) ? SCLOG : 1.0f;
      u16* dst = (n < 1024) ? Qb : (n < 2048) ? Kb : Vb;
      const int nl = n & 1023;
      const int hh = nl >> 6, d0 = nl & 63;
      uint2 pk;
      pk.x = pk_bf16((acc[i][j][0] + b4.x) * scl, (acc[i][j][1] + b4.y) * scl);
      pk.y = pk_bf16((acc[i][j][2] + b4.z) * scl, (acc[i][j][3] + b4.w) * scl);
      *reinterpret_cast<uint2*>(dst + ((size_t)(bb * 16 + hh) * 2048 + t) * 64 + d0) = pk;
    }
  }
}

// ------------------------------------------------------------ V transpose
__global__ __launch_bounds__(256) void transpose_v_kernel(const u16* __restrict__ Vb,
                                                          u16* __restrict__ VT) {
  __shared__ u16 tile[64][68];
  const int tid = threadIdx.x;
  const int tt = blockIdx.x & 31;
  const int bh = blockIdx.x >> 5;
  const size_t base = (size_t)bh * 2048 * 64;
  const int t0 = tt * 64;
#pragma unroll
  for (int p = 0; p < 2; ++p) {
    int i = p * 256 + tid;
    int row = i >> 3, ch = i & 7;
    *reinterpret_cast<short8*>(&tile[row][ch * 8]) =
        *reinterpret_cast<const short8*>(Vb + base + (size_t)(t0 + row) * 64 + ch * 8);
  }
  __syncthreads();
#pragma unroll
  for (int p = 0; p < 2; ++p) {
    int i = p * 256 + tid;
    int d = i >> 3, ch = i & 7;
    short8 v;
#pragma unroll
    for (int j = 0; j < 8; ++j) v[j] = tile[ch * 8 + j][d];
    *reinterpret_cast<short8*>(VT + base + (size_t)d * 2048 + t0 + ch * 8) = v;
  }
}

// ---------------------------------------------------------------- attention
// 32x32 MFMA version: 1 wave = one 32-row q-tile. S^T = mfma32(K,Q) (q = lane&31),
// P stays IN REGISTER (cvt_pk + v_permlane32_swap builds PV B-frags; no p_lds),
// PV = mfma32(VT, P) keeps q lane-local. Max-free softmax. K/V staged with
// slot^(row&7) both-sides swizzle. Block = 4 waves x tiles {p,31-p,32+p,63-p}.
static __device__ __forceinline__ void attn_tile32(
    f32x16& O0, f32x16& O1, float& lacc, const short8 qf[4],
    const u16* __restrict__ Kb_, const u16* __restrict__ Vb_,
    unsigned long long w, int l31, int hi) {
  f32x16 s0 = {}, s1 = {};
  const int r7 = l31 & 7;
  __builtin_amdgcn_s_setprio(1);
#pragma unroll
  for (int dc = 0; dc < 4; ++dc) {
    const int sl = (dc * 2 + hi) ^ r7;
    const short8 kf0 = *reinterpret_cast<const short8*>(&Kb_[l31 * 64 + sl * 8]);
    const short8 kf1 = *reinterpret_cast<const short8*>(&Kb_[(32 + l31) * 64 + sl * 8]);
    s0 = MFMA32(kf0, qf[dc], s0);
    s1 = MFMA32(kf1, qf[dc], s1);
  }
  __builtin_amdgcn_s_setprio(0);

  const bool full = __all(w == ~0ull);
  float ls = 0.f;
#pragma unroll
  for (int kc2 = 0; kc2 < 2; ++kc2) {
    f32x16 sv = kc2 ? s1 : s0;
    if (!full) {
      const unsigned fk = ((unsigned)(w >> (kc2 * 32))) >> (4 * hi);
#pragma unroll
      for (int g = 0; g < 4; ++g)
#pragma unroll
        for (int e = 0; e < 4; ++e)
          if (!((fk >> (8 * g + e)) & 1u)) sv[g * 4 + e] = -1e30f;
    }
    float pe[16];
#pragma unroll
    for (int r = 0; r < 16; ++r) { pe[r] = exp2f(sv[r]); ls += pe[r]; }
    unsigned u0 = pk_bf16(pe[0], pe[1]),  u1 = pk_bf16(pe[2], pe[3]);
    unsigned u2 = pk_bf16(pe[4], pe[5]),  u3 = pk_bf16(pe[6], pe[7]);
    unsigned u4 = pk_bf16(pe[8], pe[9]),  u5 = pk_bf16(pe[10], pe[11]);
    unsigned u6 = pk_bf16(pe[12], pe[13]), u7 = pk_bf16(pe[14], pe[15]);
    // half-swaps: lanes<32 keep low-k half, receive partner's; vice versa.
    asm volatile("v_permlane32_swap_b32 %0, %1" : "+v"(u0), "+v"(u2));
    asm volatile("v_permlane32_swap_b32 %0, %1" : "+v"(u1), "+v"(u3));
    asm volatile("v_permlane32_swap_b32 %0, %1" : "+v"(u4), "+v"(u6));
    asm volatile("v_permlane32_swap_b32 %0, %1" : "+v"(u5), "+v"(u7));
    uint32x4 f0; f0[0] = u0; f0[1] = u1; f0[2] = u2; f0[3] = u3;
    uint32x4 f1; f1[0] = u4; f1[1] = u5; f1[2] = u6; f1[3] = u7;
#pragma unroll
    for (int j = 0; j < 2; ++j) {
      const short8 pa = __builtin_bit_cast(short8, j ? f1 : f0);
      const int kc = kc2 * 2 + j;
      const int sl = (kc * 2 + hi) ^ r7;
      const short8 vf0 = *reinterpret_cast<const short8*>(&Vb_[l31 * 64 + sl * 8]);
      const short8 vf1 = *reinterpret_cast<const short8*>(&Vb_[(32 + l31) * 64 + sl * 8]);
      __builtin_amdgcn_s_setprio(1);
      O0 = MFMA32(vf0, pa, O0);
      O1 = MFMA32(vf1, pa, O1);
      __builtin_amdgcn_s_setprio(0);
    }
  }
  lacc += ls;
}

__global__ __launch_bounds__(256, 2) void attn_kernel(
    const u16* __restrict__ Q, const u16* __restrict__ K, const u16* __restrict__ VT,
    const unsigned long long* __restrict__ MB, u16* __restrict__ AO) {
  __shared__ u16 K_lds[2][4096];   // [64 k][64 d], slot-swizzled
  __shared__ u16 V_lds[2][4096];   // [64 d][64 k], slot-swizzled
  __shared__ unsigned act_s[4];

  const int tid = threadIdx.x;
  const int wid = tid >> 6, lane = tid & 63;
  const int l31 = lane & 31, hi = lane >> 5;

  const int wgid = blockIdx.x;          // 0..511
  const int x = wgid & 7, s = wgid >> 3;  // s 0..63
  const int g = x + 8 * (s >> 4);         // (h,b) 0..31 (XCD-grouped)
  const int p = s & 15;
  const int h = g & 15, b = g >> 4;
  const size_t bh_off = ((size_t)(b * 16 + h)) * 2048 * 64;

  const int qt = (wid == 0) ? p : (wid == 1) ? 31 - p : (wid == 2) ? 32 + p : 63 - p;
  const int qbase = qt * 32;
  const int q = qbase + l31;

  // per-wave active-tile bitmap
  {
    unsigned long long orw = 0;
#pragma unroll
    for (int i = 0; i < 16; ++i)
      orw |= MB[(size_t)(qbase + hi * 16 + i) * 32 + l31];
    const unsigned long long bal = __ballot(orw != 0);
    if (lane == 0) act_s[wid] = (unsigned)bal | (unsigned)(bal >> 32);
  }

  // Q fragments: B-operand, col q = lane&31, k(d) = dc*16 + hi*8 + e
  short8 qf[4];
  {
    const short8* qp8 = reinterpret_cast<const short8*>(Q + bh_off + (size_t)q * 64);
#pragma unroll
    for (int dc = 0; dc < 4; ++dc) qf[dc] = qp8[dc * 2 + hi];
  }

  f32x16 O0 = {}, O1 = {};
  float lacc = 0.f;

  // staging offsets (linear LDS dest; source pre-inverse-swizzled, rule #21)
  int offK[2], offV[2], ldsi[2];
#pragma unroll
  for (int pp = 0; pp < 2; ++pp) {
    const int i = pp * 256 + tid;
    const int row = i >> 3, cs = i & 7;
    const int c = cs ^ (row & 7);
    offK[pp] = row * 64 + c * 8;     // + kt*4096   (row = k)
    offV[pp] = row * 2048 + c * 8;   // + kt*64     (row = d)
    ldsi[pp] = i * 8;
  }
  const u16* Kg = K + bh_off;
  const u16* Vg = VT + bh_off;

  __syncthreads();
  const unsigned actW = act_s[wid];
  unsigned rem = act_s[0] | act_s[1] | act_s[2] | act_s[3];
  int buf = 0;

#define STAGE_TILE(bb, ktv)                                        \
  do {                                                             \
    const u16* ksrc_ = Kg + (ktv) * 4096;                          \
    const u16* vsrc_ = Vg + (ktv) * 64;                            \
    _Pragma("unroll") for (int p_ = 0; p_ < 2; ++p_) {             \
      gload_lds16(ksrc_ + offK[p_], &K_lds[bb][ldsi[p_]]);         \
      gload_lds16(vsrc_ + offV[p_], &V_lds[bb][ldsi[p_]]);         \
    }                                                              \
  } while (0)

  if (rem) {
    int kt = __ffs(rem) - 1;
    unsigned long long w_cur = MB[(size_t)q * 32 + kt];
    STAGE_TILE(0, kt);
    __syncthreads();

    while (true) {
      rem &= rem - 1;
      int ktn = -1;
      unsigned long long w_next = 0;
      if (rem) {
        ktn = __ffs(rem) - 1;
        w_next = MB[(size_t)q * 32 + ktn];
        STAGE_TILE(buf ^ 1, ktn);
      }

      if ((actW >> kt) & 1u)
        attn_tile32(O0, O1, lacc, qf, &K_lds[buf][0], &V_lds[buf][0], w_cur, l31, hi);

      if (ktn < 0) break;
      __syncthreads();
      buf ^= 1;
      kt = ktn;
      w_cur = w_next;
    }
  }
#undef STAGE_TILE

  // epilogue: O[dt][r] -> d = dt*32 + (r&3) + 8*(r>>2) + 4*hi; q = lane&31
  {
    const float lr = lacc + __shfl_xor(lacc, 32);
    const float inv = (lr > 0.f) ? (1.0f / lr) : 0.f;
    u16* dst = AO + ((size_t)(b * 2048 + q)) * 1024 + h * 64;
#pragma unroll
    for (int dt = 0; dt < 2; ++dt) {
      const f32x16 Ov = dt ? O1 : O0;
#pragma unroll
      for (int gg = 0; gg < 4; ++gg) {
        uint2 pk;
        pk.x = pk_bf16(Ov[gg * 4 + 0] * inv, Ov[gg * 4 + 1] * inv);
        pk.y = pk_bf16(Ov[gg * 4 + 2] * inv, Ov[gg * 4 + 3] * inv);
        *reinterpret_cast<uint2*>(dst + dt * 32 + gg * 8 + hi * 4) = pk;
      }
    }
  }
}

// ---------------------------------------------------------------- out GEMM
// (R12: BK=32 2-phase + XCD swizzle.)
__global__ __launch_bounds__(256) void gemm_out_kernel(
    const u16* __restrict__ A, const u16* __restrict__ BT,
    const float* __restrict__ bo, float* __restrict__ out) {
  __shared__ u16 As[128 * 32];
  __shared__ u16 Bs[128 * 32];
  const int tid = threadIdx.x;
  const int lane = tid & 63, wid = tid >> 6;
  const int l15 = lane & 15, lg = lane >> 4;
  const int wg = blockIdx.x;            // 256 = 8 XCDs x 32 m
  const int n0 = (wg & 7) * 128;
  const int m0 = (wg >> 3) * 128;
  const int wr = wid >> 1, wc = wid & 1;

  f32x4 acc[4][4] = {};

  for (int kt = 0; kt < 32; ++kt) {
    __syncthreads();
#pragma unroll
    for (int p = 0; p < 2; ++p) {
      const int c = p * 256 + tid;
      const int r = c >> 2, ch = c & 3;
      gload_lds16(A + (size_t)(m0 + r) * 1024 + kt * 32 + ch * 8,
                  &As[(p * 256 + wid * 64) * 8]);
      gload_lds16(BT + (size_t)(n0 + r) * 1024 + kt * 32 + ch * 8,
                  &Bs[(p * 256 + wid * 64) * 8]);
    }
    __syncthreads();
    short8 af[4], bfr[4];
#pragma unroll
    for (int i = 0; i < 4; ++i) {
      af[i] = *reinterpret_cast<const short8*>(&As[(wr * 64 + i * 16 + l15) * 32 + lg * 8]);
      bfr[i] = *reinterpret_cast<const short8*>(&Bs[(wc * 64 + i * 16 + l15) * 32 + lg * 8]);
    }
#pragma unroll
    for (int i = 0; i < 4; ++i)
#pragma unroll
      for (int j = 0; j < 4; ++j)
        acc[i][j] = __builtin_amdgcn_mfma_f32_16x16x32_bf16(bfr[j], af[i], acc[i][j], 0, 0, 0);
  }

#pragma unroll
  for (int i = 0; i < 4; ++i) {
    const int m = m0 + wr * 64 + i * 16 + l15;
#pragma unroll
    for (int j = 0; j < 4; ++j) {
      const int n = n0 + wc * 64 + j * 16 + lg * 4;
      const float4 b4 = *reinterpret_cast<const float4*>(bo + n);
      float4 o4;
      o4.x = acc[i][j][0] + b4.x;
      o4.y = acc[i][j][1] + b4.y;
      o4.z = acc[i][j][2] + b4.z;
      o4.w = acc[i][j][3] + b4.w;
      *reinterpret_cast<float4*>(out + (size_t)m * 1024 + n) = o4;
    }
  }
}

// ---------------------------------------------------------------- launcher
extern "C" void kernel_launch(void* const* d_in, const int* in_sizes, int n_in,
                              void* d_out, int out_size, void* d_ws, size_t ws_size,
                              hipStream_t stream) {
  (void)in_sizes; (void)n_in; (void)out_size; (void)ws_size;
  const float* hs = (const float*)d_in[0];
  const int* mask = (const int*)d_in[1];
  const float* Wq = (const float*)d_in[2];
  const float* bq = (const float*)d_in[3];
  const float* Wk = (const float*)d_in[4];
  const float* bk = (const float*)d_in[5];
  const float* Wv = (const float*)d_in[6];
  const float* bv = (const float*)d_in[7];
  const float* Wo = (const float*)d_in[8];
  const float* bo = (const float*)d_in[9];
  float* out = (float*)d_out;

  uint8_t* ws = (uint8_t*)d_ws;
  u16* X  = (u16*)(ws);                          // 8 MiB (dead after gemm_qkv)
  u16* WT = (u16*)(ws + ((size_t)8 << 20));      // 8 MiB
  u16* Qb = (u16*)(ws + ((size_t)16 << 20));     // 8 MiB
  u16* Kb = (u16*)(ws + ((size_t)24 << 20));     // 8 MiB
  u16* Vb = (u16*)(ws + ((size_t)32 << 20));     // 8 MiB
  u16* AO = (u16*)(ws + ((size_t)40 << 20));     // 8 MiB
  unsigned long long* MB = (unsigned long long*)(ws + ((size_t)48 << 20));  // 512 KiB
  u16* VbT = X;                                  // reuse X region for V^T

  prep_kernel<<<dim3(24576), dim3(256), 0, stream>>>(hs, mask, Wq, Wk, Wv, Wo, X, WT, MB);
  gemm_qkv_kernel<<<dim3(768), dim3(256), 0, stream>>>(X, WT, bq, bk, bv, Qb, Kb, Vb);
  transpose_v_kernel<<<dim3(1024), dim3(256), 0, stream>>>(Vb, VbT);
  attn_kernel<<<dim3(512), dim3(256), 0, stream>>>(Qb, Kb, VbT, MB, AO);
  gemm_out_kernel<<<dim3(256), dim3(256), 0, stream>>>(AO, WT + (size_t)3072 * 1024, bo, out);
}